// Round 4
// baseline (217.073 us; speedup 1.0000x reference)
//
#include <hip/hip_runtime.h>
#include <float.h>
#include <math.h>
#include <limits.h>

#define NSAMP 100
#define IMG_W 2048
#define IMG_H 2048
#define LANES_PER_PT 4
#define SEG 25   // centers per lane (last lane gets 23)

typedef _Float16 h2_t __attribute__((ext_vector_type(2), aligned(2)));
typedef _Float16 h8_t __attribute__((ext_vector_type(8), aligned(16)));

// fp32 -> fp16 image conversion (8 floats/thread); block 0 also zeroes accum state.
__global__ __launch_bounds__(256) void convert_kernel(const float* __restrict__ in,
                                                      _Float16* __restrict__ out,
                                                      double* __restrict__ accum,
                                                      unsigned int* __restrict__ done) {
    if (blockIdx.x == 0 && threadIdx.x == 0) { *accum = 0.0; *done = 0u; }
    int idx = blockIdx.x * blockDim.x + threadIdx.x;
    const float4* in4 = (const float4*)in;
    float4 a = in4[2 * idx];
    float4 b = in4[2 * idx + 1];
    h8_t o;
    o[0] = (_Float16)a.x; o[1] = (_Float16)a.y; o[2] = (_Float16)a.z; o[3] = (_Float16)a.w;
    o[4] = (_Float16)b.x; o[5] = (_Float16)b.y; o[6] = (_Float16)b.z; o[7] = (_Float16)b.w;
    *(h8_t*)(out + 8 * idx) = o;
}

__device__ __forceinline__ float bilin16(const _Float16* __restrict__ img, float x, float y) {
    // x,y already clipped to [0, 2047]
    float x0f = floorf(x), y0f = floorf(y);
    float wx = x - x0f, wy = y - y0f;
    int x0 = (int)x0f;
    int y0 = (int)y0f;
    int y1 = min(y0 + 1, IMG_H - 1);
    int xa = min(x0, IMG_W - 2);          // pair base; if x0==2047 shift left one
    bool edge = (x0 == IMG_W - 1);        // then wx==0, v01 weight is exactly 0
    h2_t p0 = *(const h2_t*)(img + y0 * IMG_W + xa);
    h2_t p1 = *(const h2_t*)(img + y1 * IMG_W + xa);
    float v00 = edge ? (float)p0[1] : (float)p0[0];
    float v01 = (float)p0[1];
    float v10 = edge ? (float)p1[1] : (float)p1[0];
    float v11 = (float)p1[1];
    return v00 * (1.f - wx) * (1.f - wy) + v01 * wx * (1.f - wy)
         + v10 * (1.f - wx) * wy       + v11 * wx * wy;
}

__device__ __forceinline__ float tparam(int s) {
    // matches np.linspace(0,1,100), bitwise-verified in rounds 1-3
    return (s == NSAMP - 1) ? 1.0f : (float)((double)s * (1.0 / 99.0));
}

__global__ __launch_bounds__(256) void contour_loss_kernel(
        const _Float16* __restrict__ img,
        const float* __restrict__ points,
        const float* __restrict__ normals,
        double* __restrict__ accum,
        unsigned int* __restrict__ done,
        float* __restrict__ out,
        int N, int nblocks) {
    int t = blockIdx.x * blockDim.x + threadIdx.x;
    int i = t >> 2;        // point index
    int seg = t & 3;       // which quarter of the line this lane covers
    float sq = 0.f;
    if (i < N) {
        float px = fminf(fmaxf(points[2 * i],     0.f), 2047.f);
        float py = fminf(fmaxf(points[2 * i + 1], 0.f), 2047.f);
        float nx = normals[2 * i];
        float ny = normals[2 * i + 1];
        float ddx = -ny, ddy = nx;
        float nrm = sqrtf(ddx * ddx + ddy * ddy);
        float dx = ddx / nrm, dy = ddy / nrm;

        const float maxf = FLT_MAX;
        float sdx = (dx != 0.f) ? dx : 1.f;
        float sdy = (dy != 0.f) ? dy : 1.f;
        float t_left   = (dx != 0.f) ? (0.f    - px) / sdx : -maxf;
        float t_right  = (dx != 0.f) ? (2047.f - px) / sdx :  maxf;
        float t_top    = (dy != 0.f) ? (0.f    - py) / sdy : -maxf;
        float t_bottom = (dy != 0.f) ? (2047.f - py) / sdy :  maxf;
        float t_min = fmaxf(t_left, t_top);
        float t_max = fminf(t_right, t_bottom);

        float p1x = px + t_min * dx, p1y = py + t_min * dy;
        float p2x = px + t_max * dx, p2y = py + t_max * dy;
        float vx = p2x - p1x, vy = p2y - p1y;

        // ref_val only needed by seg 0
        float ref_val = 0.f;
        if (seg == 0) ref_val = bilin16(img, px, py);

        // this lane's sample range: [s_begin, s_end] inclusive; centers s_begin+1 .. s_end-1
        int s_begin = SEG * seg;
        int s_end   = min(s_begin + SEG + 1, NSAMP - 1);

        float tt = tparam(s_begin);
        float lx = fminf(fmaxf(p1x + tt * vx, 0.f), 2047.f);
        float ly = fminf(fmaxf(p1y + tt * vy, 0.f), 2047.f);
        float v_im1 = bilin16(img, lx, ly);
        tt = tparam(s_begin + 1);
        lx = fminf(fmaxf(p1x + tt * vx, 0.f), 2047.f);
        ly = fminf(fmaxf(p1y + tt * vy, 0.f), 2047.f);
        float v_i = bilin16(img, lx, ly);
        float cx = lx, cy = ly;

        float best_d2  = INFINITY;
        int   best_idx = INT_MAX;
        float best_val = 0.f;
        if (seg == 0) {      // default candidate: argmin(all-inf)==0 -> vals[1]
            best_idx = 0;
            best_val = v_i;  // v at global sample index 1
        }

        #pragma unroll 4
        for (int s = s_begin + 2; s <= s_end; ++s) {
            float ts = tparam(s);
            float nlx = fminf(fmaxf(p1x + ts * vx, 0.f), 2047.f);
            float nly = fminf(fmaxf(p1y + ts * vy, 0.f), 2047.f);
            float v_ip1 = bilin16(img, nlx, nly);
            // center sample index = s-1
            if (v_i < v_im1 && v_i < v_ip1) {
                float ex = cx - px, ey = cy - py;
                float d2 = ex * ex + ey * ey;
                if (d2 < best_d2) { best_d2 = d2; best_idx = s - 1; best_val = v_i; }
            }
            v_im1 = v_i; v_i = v_ip1; cx = nlx; cy = nly;
        }

        // reduce candidates across the 4 lanes of this point (4 | 64 so no wave straddle)
        #pragma unroll
        for (int m = 1; m <= 2; m <<= 1) {
            float od2  = __shfl_xor(best_d2, m);
            int   oidx = __shfl_xor(best_idx, m);
            float oval = __shfl_xor(best_val, m);
            if (od2 < best_d2 || (od2 == best_d2 && oidx < best_idx)) {
                best_d2 = od2; best_idx = oidx; best_val = oval;
            }
        }

        if (seg == 0) {
            float diff = best_val - ref_val;
            sq = diff * diff;
        }
    }

    // wave (64-lane) shuffle reduction
    for (int off = 32; off > 0; off >>= 1)
        sq += __shfl_down(sq, off);
    __shared__ float wsum[4];
    int lane = threadIdx.x & 63;
    int wid  = threadIdx.x >> 6;
    if (lane == 0) wsum[wid] = sq;
    __syncthreads();
    if (threadIdx.x == 0) {
        float bs = wsum[0] + wsum[1] + wsum[2] + wsum[3];
        atomicAdd(accum, (double)bs);
        __threadfence();
        unsigned int prev = atomicAdd(done, 1u);
        if (prev == (unsigned int)(nblocks - 1)) {
            double total = atomicAdd(accum, 0.0);  // device-scope coherent read
            out[0] = (float)(total / (double)N);
        }
    }
}

extern "C" void kernel_launch(void* const* d_in, const int* in_sizes, int n_in,
                              void* d_out, int out_size, void* d_ws, size_t ws_size,
                              hipStream_t stream) {
    const float* img     = (const float*)d_in[0];
    const float* points  = (const float*)d_in[1];
    const float* normals = (const float*)d_in[2];
    int N = in_sizes[1] / 2;
    float* out = (float*)d_out;

    // d_ws layout: [0, 8 MiB) fp16 image; then accum (double); then done (uint)
    _Float16* img16 = (_Float16*)d_ws;
    double* accum = (double*)((char*)d_ws + (size_t)IMG_W * IMG_H * sizeof(_Float16));
    unsigned int* done = (unsigned int*)(accum + 1);

    int conv_threads = (IMG_W * IMG_H) / 8;           // 8 floats per thread
    convert_kernel<<<conv_threads / 256, 256, 0, stream>>>(img, img16, accum, done);

    int block = 256;
    int threads_needed = N * LANES_PER_PT;
    int grid = (threads_needed + block - 1) / block;
    contour_loss_kernel<<<grid, block, 0, stream>>>(img16, points, normals,
                                                    accum, done, out, N, grid);
}

// Round 5
// 201.136 us; speedup vs baseline: 1.0792x; 1.0792x over previous
//
#include <hip/hip_runtime.h>
#include <float.h>
#include <math.h>
#include <limits.h>

#define NSAMP 100
#define IMG_W 2048
#define IMG_H 2048
#define LANES_PER_PT 4
#define SEG 25        // centers per lane (last lane gets 23)
#define NT 64         // theta bins
#define NR 256        // rho bins
#define NB (NT * NR)  // 16384 buckets

typedef _Float16 h2_t __attribute__((ext_vector_type(2), aligned(2)));
typedef _Float16 h8_t __attribute__((ext_vector_type(8), aligned(16)));

// fp32 -> fp16 image conversion (8 floats/thread); low blocks also zero
// the histogram and accumulator state (all consumed only by later kernels).
__global__ __launch_bounds__(256) void convert_kernel(const float* __restrict__ in,
                                                      _Float16* __restrict__ out,
                                                      unsigned int* __restrict__ hist,
                                                      double* __restrict__ accum,
                                                      unsigned int* __restrict__ done) {
    int idx = blockIdx.x * blockDim.x + threadIdx.x;
    if (idx == 0) { *accum = 0.0; *done = 0u; }
    if (idx < NB) hist[idx] = 0u;
    const float4* in4 = (const float4*)in;
    float4 a = in4[2 * idx];
    float4 b = in4[2 * idx + 1];
    h8_t o;
    o[0] = (_Float16)a.x; o[1] = (_Float16)a.y; o[2] = (_Float16)a.z; o[3] = (_Float16)a.w;
    o[4] = (_Float16)b.x; o[5] = (_Float16)b.y; o[6] = (_Float16)b.z; o[7] = (_Float16)b.w;
    *(h8_t*)(out + 8 * idx) = o;
}

// Hough-space binning: bucket = (theta_bin, rho_bin) of each point's chord.
__global__ __launch_bounds__(256) void bin_kernel(const float* __restrict__ points,
                                                  const float* __restrict__ normals,
                                                  unsigned int* __restrict__ hist,
                                                  unsigned int* __restrict__ bucket,
                                                  int N) {
    int i = blockIdx.x * blockDim.x + threadIdx.x;
    if (i >= N) return;
    float px = fminf(fmaxf(points[2 * i],     0.f), 2047.f);
    float py = fminf(fmaxf(points[2 * i + 1], 0.f), 2047.f);
    float nx = normals[2 * i];
    float ny = normals[2 * i + 1];
    float ddx = -ny, ddy = nx;
    float nrm = sqrtf(ddx * ddx + ddy * ddy);
    float dx = ddx / nrm, dy = ddy / nrm;
    // fold direction to upper half-plane so theta in [0, pi]
    if (dy < 0.f || (dy == 0.f && dx < 0.f)) { dx = -dx; dy = -dy; }
    float theta = atan2f(dy, dx);
    int tb = (int)(theta * (float)(NT / 3.14159274f));
    tb = min(max(tb, 0), NT - 1);
    // signed distance of chord from image center
    float rho = (px - 1023.5f) * (-dy) + (py - 1023.5f) * dx;
    int rb = (int)((rho + 1448.f) * (NR / 2896.f));
    rb = min(max(rb, 0), NR - 1);
    unsigned int b = (unsigned int)(tb * NR + rb);
    bucket[i] = b;
    atomicAdd(&hist[b], 1u);
}

// Exclusive prefix sum over NB=16384 buckets; single block of 256 threads.
__global__ __launch_bounds__(256) void scan_kernel(const unsigned int* __restrict__ hist,
                                                   unsigned int* __restrict__ offs) {
    __shared__ unsigned int s[256];
    int t = threadIdx.x;
    int base = t * (NB / 256);
    unsigned int sum = 0;
    for (int k = 0; k < NB / 256; ++k) sum += hist[base + k];
    s[t] = sum;
    __syncthreads();
    for (int off = 1; off < 256; off <<= 1) {
        unsigned int v = (t >= off) ? s[t - off] : 0u;
        __syncthreads();
        s[t] += v;
        __syncthreads();
    }
    unsigned int run = (t == 0) ? 0u : s[t - 1];
    for (int k = 0; k < NB / 256; ++k) {
        offs[base + k] = run;
        run += hist[base + k];
    }
}

// Scatter point indices into bucket order.
__global__ __launch_bounds__(256) void scatter_kernel(const unsigned int* __restrict__ bucket,
                                                      unsigned int* __restrict__ offs,
                                                      unsigned int* __restrict__ perm,
                                                      int N) {
    int i = blockIdx.x * blockDim.x + threadIdx.x;
    if (i >= N) return;
    unsigned int pos = atomicAdd(&offs[bucket[i]], 1u);
    perm[pos] = (unsigned int)i;
}

__device__ __forceinline__ float bilin16(const _Float16* __restrict__ img, float x, float y) {
    // x,y already clipped to [0, 2047]
    float x0f = floorf(x), y0f = floorf(y);
    float wx = x - x0f, wy = y - y0f;
    int x0 = (int)x0f;
    int y0 = (int)y0f;
    int y1 = min(y0 + 1, IMG_H - 1);
    int xa = min(x0, IMG_W - 2);          // pair base; if x0==2047 shift left one
    bool edge = (x0 == IMG_W - 1);        // then wx==0, v01 weight is exactly 0
    h2_t p0 = *(const h2_t*)(img + y0 * IMG_W + xa);
    h2_t p1 = *(const h2_t*)(img + y1 * IMG_W + xa);
    float v00 = edge ? (float)p0[1] : (float)p0[0];
    float v01 = (float)p0[1];
    float v10 = edge ? (float)p1[1] : (float)p1[0];
    float v11 = (float)p1[1];
    return v00 * (1.f - wx) * (1.f - wy) + v01 * wx * (1.f - wy)
         + v10 * (1.f - wx) * wy       + v11 * wx * wy;
}

__device__ __forceinline__ float tparam(int s) {
    // matches np.linspace(0,1,100), bitwise-verified in rounds 1-4
    return (s == NSAMP - 1) ? 1.0f : (float)((double)s * (1.0 / 99.0));
}

__global__ __launch_bounds__(256) void contour_loss_kernel(
        const _Float16* __restrict__ img,
        const float* __restrict__ points,
        const float* __restrict__ normals,
        const unsigned int* __restrict__ perm,
        double* __restrict__ accum,
        unsigned int* __restrict__ done,
        float* __restrict__ out,
        int N, int nblocks) {
    int t = blockIdx.x * blockDim.x + threadIdx.x;
    int slot = t >> 2;     // sorted position
    int seg = t & 3;       // which quarter of the line this lane covers
    float sq = 0.f;
    if (slot < N) {
        int i = (int)perm[slot];   // actual point index (bucket-sorted order)
        float px = fminf(fmaxf(points[2 * i],     0.f), 2047.f);
        float py = fminf(fmaxf(points[2 * i + 1], 0.f), 2047.f);
        float nx = normals[2 * i];
        float ny = normals[2 * i + 1];
        float ddx = -ny, ddy = nx;
        float nrm = sqrtf(ddx * ddx + ddy * ddy);
        float dx = ddx / nrm, dy = ddy / nrm;

        const float maxf = FLT_MAX;
        float sdx = (dx != 0.f) ? dx : 1.f;
        float sdy = (dy != 0.f) ? dy : 1.f;
        float t_left   = (dx != 0.f) ? (0.f    - px) / sdx : -maxf;
        float t_right  = (dx != 0.f) ? (2047.f - px) / sdx :  maxf;
        float t_top    = (dy != 0.f) ? (0.f    - py) / sdy : -maxf;
        float t_bottom = (dy != 0.f) ? (2047.f - py) / sdy :  maxf;
        float t_min = fmaxf(t_left, t_top);
        float t_max = fminf(t_right, t_bottom);

        float p1x = px + t_min * dx, p1y = py + t_min * dy;
        float p2x = px + t_max * dx, p2y = py + t_max * dy;
        float vx = p2x - p1x, vy = p2y - p1y;

        float ref_val = 0.f;
        if (seg == 0) ref_val = bilin16(img, px, py);

        int s_begin = SEG * seg;
        int s_end   = min(s_begin + SEG + 1, NSAMP - 1);

        float tt = tparam(s_begin);
        float lx = fminf(fmaxf(p1x + tt * vx, 0.f), 2047.f);
        float ly = fminf(fmaxf(p1y + tt * vy, 0.f), 2047.f);
        float v_im1 = bilin16(img, lx, ly);
        tt = tparam(s_begin + 1);
        lx = fminf(fmaxf(p1x + tt * vx, 0.f), 2047.f);
        ly = fminf(fmaxf(p1y + tt * vy, 0.f), 2047.f);
        float v_i = bilin16(img, lx, ly);
        float cx = lx, cy = ly;

        float best_d2  = INFINITY;
        int   best_idx = INT_MAX;
        float best_val = 0.f;
        if (seg == 0) {      // default candidate: argmin(all-inf)==0 -> vals[1]
            best_idx = 0;
            best_val = v_i;
        }

        #pragma unroll 4
        for (int s = s_begin + 2; s <= s_end; ++s) {
            float ts = tparam(s);
            float nlx = fminf(fmaxf(p1x + ts * vx, 0.f), 2047.f);
            float nly = fminf(fmaxf(p1y + ts * vy, 0.f), 2047.f);
            float v_ip1 = bilin16(img, nlx, nly);
            if (v_i < v_im1 && v_i < v_ip1) {
                float ex = cx - px, ey = cy - py;
                float d2 = ex * ex + ey * ey;
                if (d2 < best_d2) { best_d2 = d2; best_idx = s - 1; best_val = v_i; }
            }
            v_im1 = v_i; v_i = v_ip1; cx = nlx; cy = nly;
        }

        // reduce across the point's 4 lanes (4 | 64, no wave straddle)
        #pragma unroll
        for (int m = 1; m <= 2; m <<= 1) {
            float od2  = __shfl_xor(best_d2, m);
            int   oidx = __shfl_xor(best_idx, m);
            float oval = __shfl_xor(best_val, m);
            if (od2 < best_d2 || (od2 == best_d2 && oidx < best_idx)) {
                best_d2 = od2; best_idx = oidx; best_val = oval;
            }
        }

        if (seg == 0) {
            float diff = best_val - ref_val;
            sq = diff * diff;
        }
    }

    // wave (64-lane) shuffle reduction
    for (int off = 32; off > 0; off >>= 1)
        sq += __shfl_down(sq, off);
    __shared__ float wsum[4];
    int lane = threadIdx.x & 63;
    int wid  = threadIdx.x >> 6;
    if (lane == 0) wsum[wid] = sq;
    __syncthreads();
    if (threadIdx.x == 0) {
        float bs = wsum[0] + wsum[1] + wsum[2] + wsum[3];
        atomicAdd(accum, (double)bs);
        __threadfence();
        unsigned int prev = atomicAdd(done, 1u);
        if (prev == (unsigned int)(nblocks - 1)) {
            double total = atomicAdd(accum, 0.0);  // device-scope coherent read
            out[0] = (float)(total / (double)N);
        }
    }
}

extern "C" void kernel_launch(void* const* d_in, const int* in_sizes, int n_in,
                              void* d_out, int out_size, void* d_ws, size_t ws_size,
                              hipStream_t stream) {
    const float* img     = (const float*)d_in[0];
    const float* points  = (const float*)d_in[1];
    const float* normals = (const float*)d_in[2];
    int N = in_sizes[1] / 2;
    float* out = (float*)d_out;

    // d_ws layout
    char* ws = (char*)d_ws;
    _Float16* img16    = (_Float16*)ws;                          // 8 MiB
    size_t off = (size_t)IMG_W * IMG_H * sizeof(_Float16);
    double* accum      = (double*)(ws + off);        off += 8;
    unsigned int* done = (unsigned int*)(ws + off);  off += 8;   // keep 8B align
    unsigned int* hist = (unsigned int*)(ws + off);  off += NB * 4;
    unsigned int* offs = (unsigned int*)(ws + off);  off += NB * 4;
    unsigned int* bucket = (unsigned int*)(ws + off); off += (size_t)N * 4;
    unsigned int* perm = (unsigned int*)(ws + off);

    int conv_blocks = (IMG_W * IMG_H / 8) / 256;     // 8 floats per thread
    convert_kernel<<<conv_blocks, 256, 0, stream>>>(img, img16, hist, accum, done);

    int pgrid = (N + 255) / 256;
    bin_kernel<<<pgrid, 256, 0, stream>>>(points, normals, hist, bucket, N);
    scan_kernel<<<1, 256, 0, stream>>>(hist, offs);
    scatter_kernel<<<pgrid, 256, 0, stream>>>(bucket, offs, perm, N);

    int threads_needed = N * LANES_PER_PT;
    int grid = (threads_needed + 255) / 256;
    contour_loss_kernel<<<grid, 256, 0, stream>>>(img16, points, normals, perm,
                                                  accum, done, out, N, grid);
}

// Round 6
// 168.791 us; speedup vs baseline: 1.2860x; 1.1916x over previous
//
#include <hip/hip_runtime.h>
#include <float.h>
#include <math.h>
#include <limits.h>

#define NSAMP 100
#define IMG_W 2048
#define IMG_H 2048
#define NT 256        // theta bins (fine: pi/256 -> ~18px max divergence)
#define NR 128        // rho bins (2896/128 = 22.6 px)
#define NB (NT * NR)  // 32768 buckets

typedef _Float16 h2_t __attribute__((ext_vector_type(2), aligned(2)));
typedef _Float16 h8_t __attribute__((ext_vector_type(8), aligned(16)));

// fp32 -> fp16 image conversion (8 floats/thread); also zeroes hist/accum/done.
__global__ __launch_bounds__(256) void convert_kernel(const float* __restrict__ in,
                                                      _Float16* __restrict__ out,
                                                      unsigned int* __restrict__ hist,
                                                      double* __restrict__ accum,
                                                      unsigned int* __restrict__ done) {
    int idx = blockIdx.x * blockDim.x + threadIdx.x;
    if (idx == 0) { *accum = 0.0; *done = 0u; }
    if (idx < NB) hist[idx] = 0u;    // grid has 524288 threads > NB
    const float4* in4 = (const float4*)in;
    float4 a = in4[2 * idx];
    float4 b = in4[2 * idx + 1];
    h8_t o;
    o[0] = (_Float16)a.x; o[1] = (_Float16)a.y; o[2] = (_Float16)a.z; o[3] = (_Float16)a.w;
    o[4] = (_Float16)b.x; o[5] = (_Float16)b.y; o[6] = (_Float16)b.z; o[7] = (_Float16)b.w;
    *(h8_t*)(out + 8 * idx) = o;
}

// Hough-space binning: bucket = (theta_bin, rho_bin) of each point's chord.
__global__ __launch_bounds__(256) void bin_kernel(const float* __restrict__ points,
                                                  const float* __restrict__ normals,
                                                  unsigned int* __restrict__ hist,
                                                  unsigned int* __restrict__ bucket,
                                                  int N) {
    int i = blockIdx.x * blockDim.x + threadIdx.x;
    if (i >= N) return;
    float px = fminf(fmaxf(points[2 * i],     0.f), 2047.f);
    float py = fminf(fmaxf(points[2 * i + 1], 0.f), 2047.f);
    float nx = normals[2 * i];
    float ny = normals[2 * i + 1];
    float ddx = -ny, ddy = nx;
    float nrm = sqrtf(ddx * ddx + ddy * ddy);
    float dx = ddx / nrm, dy = ddy / nrm;
    // fold direction to upper half-plane so theta in [0, pi]
    if (dy < 0.f || (dy == 0.f && dx < 0.f)) { dx = -dx; dy = -dy; }
    float theta = atan2f(dy, dx);
    int tb = (int)(theta * (float)(NT / 3.14159274f));
    tb = min(max(tb, 0), NT - 1);
    // signed distance of chord from image center
    float rho = (px - 1023.5f) * (-dy) + (py - 1023.5f) * dx;
    int rb = (int)((rho + 1448.f) * ((float)NR / 2896.f));
    rb = min(max(rb, 0), NR - 1);
    unsigned int b = (unsigned int)(tb * NR + rb);
    bucket[i] = b;
    atomicAdd(&hist[b], 1u);
}

// Exclusive prefix sum over NB buckets; single block of 256 threads.
__global__ __launch_bounds__(256) void scan_kernel(const unsigned int* __restrict__ hist,
                                                   unsigned int* __restrict__ offs) {
    __shared__ unsigned int s[256];
    int t = threadIdx.x;
    int base = t * (NB / 256);
    unsigned int sum = 0;
    for (int k = 0; k < NB / 256; ++k) sum += hist[base + k];
    s[t] = sum;
    __syncthreads();
    for (int off = 1; off < 256; off <<= 1) {
        unsigned int v = (t >= off) ? s[t - off] : 0u;
        __syncthreads();
        s[t] += v;
        __syncthreads();
    }
    unsigned int run = (t == 0) ? 0u : s[t - 1];
    for (int k = 0; k < NB / 256; ++k) {
        offs[base + k] = run;
        run += hist[base + k];
    }
}

// Scatter points into bucket order, pre-gathered as float4(px,py,nx,ny)
// (px,py already clipped -- clip is idempotent so main kernel math is unchanged).
__global__ __launch_bounds__(256) void scatter_kernel(const float* __restrict__ points,
                                                      const float* __restrict__ normals,
                                                      const unsigned int* __restrict__ bucket,
                                                      unsigned int* __restrict__ offs,
                                                      float4* __restrict__ sorted,
                                                      int N) {
    int i = blockIdx.x * blockDim.x + threadIdx.x;
    if (i >= N) return;
    unsigned int pos = atomicAdd(&offs[bucket[i]], 1u);
    float4 r;
    r.x = fminf(fmaxf(points[2 * i],     0.f), 2047.f);
    r.y = fminf(fmaxf(points[2 * i + 1], 0.f), 2047.f);
    r.z = normals[2 * i];
    r.w = normals[2 * i + 1];
    sorted[pos] = r;
}

__device__ __forceinline__ float bilin16(const _Float16* __restrict__ img, float x, float y) {
    // x,y already clipped to [0, 2047]
    float x0f = floorf(x), y0f = floorf(y);
    float wx = x - x0f, wy = y - y0f;
    int x0 = (int)x0f;
    int y0 = (int)y0f;
    int y1 = min(y0 + 1, IMG_H - 1);
    int xa = min(x0, IMG_W - 2);          // pair base; if x0==2047 shift left one
    bool edge = (x0 == IMG_W - 1);        // then wx==0, v01 weight is exactly 0
    h2_t p0 = *(const h2_t*)(img + y0 * IMG_W + xa);
    h2_t p1 = *(const h2_t*)(img + y1 * IMG_W + xa);
    float v00 = edge ? (float)p0[1] : (float)p0[0];
    float v01 = (float)p0[1];
    float v10 = edge ? (float)p1[1] : (float)p1[0];
    float v11 = (float)p1[1];
    return v00 * (1.f - wx) * (1.f - wy) + v01 * wx * (1.f - wy)
         + v10 * (1.f - wx) * wy       + v11 * wx * wy;
}

__device__ __forceinline__ float tparam(int s) {
    // matches np.linspace(0,1,100), bitwise-verified in rounds 1-5
    return (s == NSAMP - 1) ? 1.0f : (float)((double)s * (1.0 / 99.0));
}

__global__ __launch_bounds__(256) void contour_loss_kernel(
        const _Float16* __restrict__ img,
        const float4* __restrict__ sorted,
        double* __restrict__ accum,
        unsigned int* __restrict__ done,
        float* __restrict__ out,
        int N, int nblocks) {
    int i = blockIdx.x * blockDim.x + threadIdx.x;
    float sq = 0.f;
    if (i < N) {
        float4 pt = sorted[i];
        float px = pt.x, py = pt.y;
        float nx = pt.z, ny = pt.w;
        float ddx = -ny, ddy = nx;
        float nrm = sqrtf(ddx * ddx + ddy * ddy);
        float dx = ddx / nrm, dy = ddy / nrm;

        const float maxf = FLT_MAX;
        float sdx = (dx != 0.f) ? dx : 1.f;
        float sdy = (dy != 0.f) ? dy : 1.f;
        float t_left   = (dx != 0.f) ? (0.f    - px) / sdx : -maxf;
        float t_right  = (dx != 0.f) ? (2047.f - px) / sdx :  maxf;
        float t_top    = (dy != 0.f) ? (0.f    - py) / sdy : -maxf;
        float t_bottom = (dy != 0.f) ? (2047.f - py) / sdy :  maxf;
        float t_min = fmaxf(t_left, t_top);
        float t_max = fminf(t_right, t_bottom);

        float p1x = px + t_min * dx, p1y = py + t_min * dy;
        float p2x = px + t_max * dx, p2y = py + t_max * dy;
        float vx = p2x - p1x, vy = p2y - p1y;

        float ref_val = bilin16(img, px, py);

        // sample s=0
        float lx = fminf(fmaxf(p1x, 0.f), 2047.f);
        float ly = fminf(fmaxf(p1y, 0.f), 2047.f);
        float v_im1 = bilin16(img, lx, ly);
        // sample s=1
        float t1 = tparam(1);
        lx = fminf(fmaxf(p1x + t1 * vx, 0.f), 2047.f);
        ly = fminf(fmaxf(p1y + t1 * vy, 0.f), 2047.f);
        float v_i = bilin16(img, lx, ly);
        float cx = lx, cy = ly;

        float best_val = v_i;     // argmin(all-inf)==0 -> vals[1]
        float best_d2  = INFINITY;

        #pragma unroll 4
        for (int s = 2; s < NSAMP; ++s) {
            float ts = tparam(s);
            float nlx = fminf(fmaxf(p1x + ts * vx, 0.f), 2047.f);
            float nly = fminf(fmaxf(p1y + ts * vy, 0.f), 2047.f);
            float v_ip1 = bilin16(img, nlx, nly);
            if (v_i < v_im1 && v_i < v_ip1) {
                float ex = cx - px, ey = cy - py;
                float d2 = ex * ex + ey * ey;
                if (d2 < best_d2) { best_d2 = d2; best_val = v_i; }
            }
            v_im1 = v_i; v_i = v_ip1; cx = nlx; cy = nly;
        }
        float diff = best_val - ref_val;
        sq = diff * diff;
    }

    // wave (64-lane) shuffle reduction
    for (int off = 32; off > 0; off >>= 1)
        sq += __shfl_down(sq, off);
    __shared__ float wsum[4];
    int lane = threadIdx.x & 63;
    int wid  = threadIdx.x >> 6;
    if (lane == 0) wsum[wid] = sq;
    __syncthreads();
    if (threadIdx.x == 0) {
        float bs = wsum[0] + wsum[1] + wsum[2] + wsum[3];
        atomicAdd(accum, (double)bs);
        __threadfence();
        unsigned int prev = atomicAdd(done, 1u);
        if (prev == (unsigned int)(nblocks - 1)) {
            double total = atomicAdd(accum, 0.0);  // device-scope coherent read
            out[0] = (float)(total / (double)N);
        }
    }
}

extern "C" void kernel_launch(void* const* d_in, const int* in_sizes, int n_in,
                              void* d_out, int out_size, void* d_ws, size_t ws_size,
                              hipStream_t stream) {
    const float* img     = (const float*)d_in[0];
    const float* points  = (const float*)d_in[1];
    const float* normals = (const float*)d_in[2];
    int N = in_sizes[1] / 2;
    float* out = (float*)d_out;

    // d_ws layout
    char* ws = (char*)d_ws;
    _Float16* img16    = (_Float16*)ws;                          // 8 MiB
    size_t off = (size_t)IMG_W * IMG_H * sizeof(_Float16);
    double* accum      = (double*)(ws + off);        off += 8;
    unsigned int* done = (unsigned int*)(ws + off);  off += 8;   // keep 8B align
    unsigned int* hist = (unsigned int*)(ws + off);  off += (size_t)NB * 4;
    unsigned int* offs = (unsigned int*)(ws + off);  off += (size_t)NB * 4;
    unsigned int* bucket = (unsigned int*)(ws + off); off += (size_t)N * 4;
    off = (off + 15) & ~(size_t)15;                   // align float4
    float4* sorted = (float4*)(ws + off);

    int conv_blocks = (IMG_W * IMG_H / 8) / 256;     // 8 floats per thread
    convert_kernel<<<conv_blocks, 256, 0, stream>>>(img, img16, hist, accum, done);

    int pgrid = (N + 255) / 256;
    bin_kernel<<<pgrid, 256, 0, stream>>>(points, normals, hist, bucket, N);
    scan_kernel<<<1, 256, 0, stream>>>(hist, offs);
    scatter_kernel<<<pgrid, 256, 0, stream>>>(points, normals, bucket, offs, sorted, N);

    int grid = (N + 255) / 256;
    contour_loss_kernel<<<grid, 256, 0, stream>>>(img16, sorted, accum, done, out, N, grid);
}

// Round 7
// 128.826 us; speedup vs baseline: 1.6850x; 1.3102x over previous
//
#include <hip/hip_runtime.h>
#include <float.h>
#include <math.h>

#define NSAMP 100
#define IMG_W 2048
#define IMG_H 2048

typedef _Float16 h2_t __attribute__((ext_vector_type(2), aligned(4)));
typedef _Float16 h4_t __attribute__((ext_vector_type(4), aligned(8)));
typedef _Float16 h8_t __attribute__((ext_vector_type(8), aligned(16)));

// Build vertical-pair fp16 texture: V[y][x] = (img[y][x], img[min(y+1,H-1)][x]).
// One thread converts 4 texels (reads float4 from rows y and y+1, writes 16 B).
// Thread 0 of block 0 also zeroes the accumulator state.
__global__ __launch_bounds__(256) void convert_kernel(const float* __restrict__ in,
                                                      h2_t* __restrict__ V,
                                                      double* __restrict__ accum,
                                                      unsigned int* __restrict__ done) {
    int idx = blockIdx.x * blockDim.x + threadIdx.x;   // 2048*512 threads
    if (idx == 0) { *accum = 0.0; *done = 0u; }
    int y  = idx >> 9;          // row 0..2047
    int x4 = (idx & 511) << 2;  // col 0,4,..,2044
    int y1 = min(y + 1, IMG_H - 1);
    float4 a = *(const float4*)(in + (size_t)y  * IMG_W + x4);
    float4 b = *(const float4*)(in + (size_t)y1 * IMG_W + x4);
    h8_t o;
    o[0] = (_Float16)a.x; o[1] = (_Float16)b.x;
    o[2] = (_Float16)a.y; o[3] = (_Float16)b.y;
    o[4] = (_Float16)a.z; o[5] = (_Float16)b.z;
    o[6] = (_Float16)a.w; o[7] = (_Float16)b.w;
    *(h8_t*)(V + (size_t)y * IMG_W + x4) = o;
}

// Bilinear via ONE 8-byte load: V[y0][xa], V[y0][xa+1] hold all 4 corners.
__device__ __forceinline__ float bilinV(const h2_t* __restrict__ V, float x, float y) {
    // x,y already clipped to [0, 2047]
    float x0f = floorf(x), y0f = floorf(y);
    float wx = x - x0f, wy = y - y0f;
    int x0 = (int)x0f;
    int y0 = (int)y0f;
    int xa = min(x0, IMG_W - 2);          // pair base; if x0==2047 shift left one
    bool edge = (x0 == IMG_W - 1);        // then wx==0, right-column weight is 0
    h4_t q = *(const h4_t*)(V + (size_t)y0 * IMG_W + xa);
    // q = (v00,v10, v01,v11) for columns xa, xa+1
    float v00 = edge ? (float)q[2] : (float)q[0];
    float v10 = edge ? (float)q[3] : (float)q[1];
    float v01 = (float)q[2];
    float v11 = (float)q[3];
    return v00 * (1.f - wx) * (1.f - wy) + v01 * wx * (1.f - wy)
         + v10 * (1.f - wx) * wy       + v11 * wx * wy;
}

__device__ __forceinline__ float tparam(int s) {
    // matches np.linspace(0,1,100), bitwise-verified in rounds 1-6
    return (s == NSAMP - 1) ? 1.0f : (float)((double)s * (1.0 / 99.0));
}

__global__ __launch_bounds__(256) void contour_loss_kernel(
        const h2_t* __restrict__ V,
        const float* __restrict__ points,
        const float* __restrict__ normals,
        double* __restrict__ accum,
        unsigned int* __restrict__ done,
        float* __restrict__ out,
        int N, int nblocks) {
    int i = blockIdx.x * blockDim.x + threadIdx.x;
    float sq = 0.f;
    if (i < N) {
        float px = fminf(fmaxf(points[2 * i],     0.f), 2047.f);
        float py = fminf(fmaxf(points[2 * i + 1], 0.f), 2047.f);
        float nx = normals[2 * i];
        float ny = normals[2 * i + 1];
        float ddx = -ny, ddy = nx;
        float nrm = sqrtf(ddx * ddx + ddy * ddy);
        float dx = ddx / nrm, dy = ddy / nrm;

        const float maxf = FLT_MAX;
        float sdx = (dx != 0.f) ? dx : 1.f;
        float sdy = (dy != 0.f) ? dy : 1.f;
        float t_left   = (dx != 0.f) ? (0.f    - px) / sdx : -maxf;
        float t_right  = (dx != 0.f) ? (2047.f - px) / sdx :  maxf;
        float t_top    = (dy != 0.f) ? (0.f    - py) / sdy : -maxf;
        float t_bottom = (dy != 0.f) ? (2047.f - py) / sdy :  maxf;
        float t_min = fmaxf(t_left, t_top);
        float t_max = fminf(t_right, t_bottom);

        float p1x = px + t_min * dx, p1y = py + t_min * dy;
        float p2x = px + t_max * dx, p2y = py + t_max * dy;
        float vx = p2x - p1x, vy = p2y - p1y;

        float ref_val = bilinV(V, px, py);

        // sample s=0
        float lx = fminf(fmaxf(p1x, 0.f), 2047.f);
        float ly = fminf(fmaxf(p1y, 0.f), 2047.f);
        float v_im1 = bilinV(V, lx, ly);
        // sample s=1
        float t1 = tparam(1);
        lx = fminf(fmaxf(p1x + t1 * vx, 0.f), 2047.f);
        ly = fminf(fmaxf(p1y + t1 * vy, 0.f), 2047.f);
        float v_i = bilinV(V, lx, ly);
        float cx = lx, cy = ly;

        float best_val = v_i;     // argmin(all-inf)==0 -> vals[1]
        float best_d2  = INFINITY;

        #pragma unroll 8
        for (int s = 2; s < NSAMP; ++s) {
            float ts = tparam(s);
            float nlx = fminf(fmaxf(p1x + ts * vx, 0.f), 2047.f);
            float nly = fminf(fmaxf(p1y + ts * vy, 0.f), 2047.f);
            float v_ip1 = bilinV(V, nlx, nly);
            if (v_i < v_im1 && v_i < v_ip1) {
                float ex = cx - px, ey = cy - py;
                float d2 = ex * ex + ey * ey;
                if (d2 < best_d2) { best_d2 = d2; best_val = v_i; }
            }
            v_im1 = v_i; v_i = v_ip1; cx = nlx; cy = nly;
        }
        float diff = best_val - ref_val;
        sq = diff * diff;
    }

    // wave (64-lane) shuffle reduction
    for (int off = 32; off > 0; off >>= 1)
        sq += __shfl_down(sq, off);
    __shared__ float wsum[4];
    int lane = threadIdx.x & 63;
    int wid  = threadIdx.x >> 6;
    if (lane == 0) wsum[wid] = sq;
    __syncthreads();
    if (threadIdx.x == 0) {
        float bs = wsum[0] + wsum[1] + wsum[2] + wsum[3];
        atomicAdd(accum, (double)bs);
        __threadfence();
        unsigned int prev = atomicAdd(done, 1u);
        if (prev == (unsigned int)(nblocks - 1)) {
            double total = atomicAdd(accum, 0.0);  // device-scope coherent read
            out[0] = (float)(total / (double)N);
        }
    }
}

extern "C" void kernel_launch(void* const* d_in, const int* in_sizes, int n_in,
                              void* d_out, int out_size, void* d_ws, size_t ws_size,
                              hipStream_t stream) {
    const float* img     = (const float*)d_in[0];
    const float* points  = (const float*)d_in[1];
    const float* normals = (const float*)d_in[2];
    int N = in_sizes[1] / 2;
    float* out = (float*)d_out;

    // d_ws layout: [0, 16 MiB) vertical-pair fp16 texture; then accum; then done
    char* ws = (char*)d_ws;
    h2_t* V = (h2_t*)ws;
    size_t off = (size_t)IMG_W * IMG_H * sizeof(h2_t);   // 16 MiB
    double* accum      = (double*)(ws + off);  off += 8;
    unsigned int* done = (unsigned int*)(ws + off);

    int conv_blocks = (IMG_W * IMG_H / 4) / 256;   // 4 texels per thread
    convert_kernel<<<conv_blocks, 256, 0, stream>>>(img, V, accum, done);

    int grid = (N + 255) / 256;
    contour_loss_kernel<<<grid, 256, 0, stream>>>(V, points, normals,
                                                  accum, done, out, N, grid);
}